// Round 1
// baseline (114.321 us; speedup 1.0000x reference)
//
#include <hip/hip_runtime.h>
#include <hip/hip_bf16.h>

// B=4, T=4096, E=512, H=64. out fp32 [B,T,H].
#define Bn 4
#define Tn 4096
#define En 512
#define Hn 64

typedef __attribute__((ext_vector_type(8))) __bf16 bf16x8;
typedef __attribute__((ext_vector_type(4))) float f32x4;

__device__ __forceinline__ unsigned short f2bf(float f) {
    union { float f; unsigned u; } v; v.f = f;
    unsigned r = v.u + 0x7fffu + ((v.u >> 16) & 1u);
    return (unsigned short)(r >> 16);
}

// ---------------- kernel 1: W fp32 -> bf16 concat [192][512] ----------------
__global__ void wcvt(const float* __restrict__ Wq, const float* __restrict__ Wk,
                     const float* __restrict__ Wv, unsigned short* __restrict__ Wo) {
    int i = blockIdx.x * 256 + threadIdx.x;      // 0..98303
    int mat = i >> 15;                            // each W is 64*512 = 32768
    int off = i & 32767;
    const float* s = (mat == 0) ? Wq : ((mat == 1) ? Wk : Wv);
    Wo[i] = f2bf(s[off]);
}

// ---------------- kernel 2: fused QKV projection (bf16 MFMA GEMM) -----------
// y = x @ Wqkv^T : M=16384 rows, N=192 cols, K=512.
// cols 0-63 -> q[row][h], 64-127 -> k[row][h], 128-191 -> v^T[b][h][t].
__launch_bounds__(256, 2)
__global__ void proj(const float* __restrict__ x, const unsigned short* __restrict__ Wo,
                     unsigned short* __restrict__ q16, unsigned short* __restrict__ k16,
                     unsigned short* __restrict__ vt16) {
    __shared__ unsigned short sA[64 * 72];   // 64 rows x 64 k, stride 72 (pad kills bank conflict)
    __shared__ unsigned short sW[192 * 72];
    const int tid = threadIdx.x;
    const int w = tid >> 6, lane = tid & 63, r = lane & 15, g = lane >> 4;
    const int row0 = blockIdx.x * 64;

    f32x4 acc[12];
#pragma unroll
    for (int i = 0; i < 12; ++i) acc[i] = (f32x4){0.f, 0.f, 0.f, 0.f};

    for (int k0 = 0; k0 < En; k0 += 64) {
        // stage A: 64x64 fp32 -> bf16 (chunks of 8)
#pragma unroll
        for (int i = 0; i < 2; ++i) {
            int c = tid + i * 256; int arow = c >> 3, kc = (c & 7) * 8;
            const float4* xp = (const float4*)&x[(row0 + arow) * En + k0 + kc];
            float4 f0 = xp[0], f1 = xp[1];
            union { bf16x8 v; unsigned short u[8]; } t;
            t.u[0] = f2bf(f0.x); t.u[1] = f2bf(f0.y); t.u[2] = f2bf(f0.z); t.u[3] = f2bf(f0.w);
            t.u[4] = f2bf(f1.x); t.u[5] = f2bf(f1.y); t.u[6] = f2bf(f1.z); t.u[7] = f2bf(f1.w);
            *(bf16x8*)&sA[arow * 72 + kc] = t.v;
        }
        // stage W: 192x64 bf16
#pragma unroll
        for (int i = 0; i < 6; ++i) {
            int c = tid + i * 256; int wrow = c >> 3, kc = (c & 7) * 8;
            bf16x8 wv = *(const bf16x8*)&Wo[wrow * En + k0 + kc];
            *(bf16x8*)&sW[wrow * 72 + kc] = wv;
        }
        __syncthreads();
        bf16x8 a0 = *(bf16x8*)&sA[(w * 16 + r) * 72 + g * 8];
        bf16x8 a1 = *(bf16x8*)&sA[(w * 16 + r) * 72 + 32 + g * 8];
#pragma unroll
        for (int ct = 0; ct < 12; ++ct) {
            bf16x8 b0 = *(bf16x8*)&sW[(ct * 16 + r) * 72 + g * 8];
            bf16x8 b1 = *(bf16x8*)&sW[(ct * 16 + r) * 72 + 32 + g * 8];
            acc[ct] = __builtin_amdgcn_mfma_f32_16x16x32_bf16(a0, b0, acc[ct], 0, 0, 0);
            acc[ct] = __builtin_amdgcn_mfma_f32_16x16x32_bf16(a1, b1, acc[ct], 0, 0, 0);
        }
        __syncthreads();
    }
    // epilogue: C layout col = lane&15, row = (lane>>4)*4 + reg  (m89-verified)
#pragma unroll
    for (int ct = 0; ct < 12; ++ct) {
        int n = ct * 16 + r;
#pragma unroll
        for (int reg = 0; reg < 4; ++reg) {
            int gr = row0 + w * 16 + g * 4 + reg;
            unsigned short bv = f2bf(acc[ct][reg]);
            if (n < 64) {
                q16[gr * 64 + n] = bv;
            } else if (n < 128) {
                k16[gr * 64 + (n - 64)] = bv;
            } else {
                int h = n - 128; int bb = gr >> 12; int t = gr & 4095;
                vt16[((bb * 64 + h) << 12) + t] = bv;
            }
        }
    }
}

// ---------------- kernel 3: causal flash attention ---------------------------
// 1024 blocks x 1 wave. Block = one 16-row q tile. kv tiles of 64.
__global__ void attn(const unsigned short* __restrict__ q16, const unsigned short* __restrict__ k16,
                     const unsigned short* __restrict__ vt16, float* __restrict__ out) {
    __shared__ unsigned short sP[16 * 72];
    const int lane = threadIdx.x & 63, r = lane & 15, g = lane >> 4;
    const int bid = blockIdx.x;
    const int b = (bid >> 1) & 3;                         // batch -> XCD pair (L2 locality)
    const int i16 = 255 - (((bid >> 3) << 1) | (bid & 1)); // longest tiles first
    const int q0 = i16 * 16;
    const int qrow = b * Tn + q0;

    bf16x8 aq0 = *(const bf16x8*)&q16[(qrow + r) * 64 + g * 8];
    bf16x8 aq1 = *(const bf16x8*)&q16[(qrow + r) * 64 + 32 + g * 8];

    f32x4 o[4];
#pragma unroll
    for (int i = 0; i < 4; ++i) o[i] = (f32x4){0.f, 0.f, 0.f, 0.f};
    float m_[4], l_[4];
#pragma unroll
    for (int i = 0; i < 4; ++i) { m_[i] = -1e30f; l_[i] = 0.f; }

    const int kbmax = i16 >> 2;
    const float scale = 0.125f;   // 1/sqrt(64)

    for (int kb = 0; kb <= kbmax; ++kb) {
        const int kv0 = kb * 64;
        f32x4 s[4];
#pragma unroll
        for (int ct = 0; ct < 4; ++ct) {
            const unsigned short* kp = &k16[(b * Tn + kv0 + ct * 16 + r) * 64 + g * 8];
            bf16x8 bk0 = *(const bf16x8*)kp;
            bf16x8 bk1 = *(const bf16x8*)(kp + 32);
            f32x4 t = (f32x4){0.f, 0.f, 0.f, 0.f};
            t = __builtin_amdgcn_mfma_f32_16x16x32_bf16(aq0, bk0, t, 0, 0, 0);
            t = __builtin_amdgcn_mfma_f32_16x16x32_bf16(aq1, bk1, t, 0, 0, 0);
            s[ct] = t;
        }
        if (kb == kbmax) {
#pragma unroll
            for (int ct = 0; ct < 4; ++ct)
#pragma unroll
                for (int reg = 0; reg < 4; ++reg) {
                    bool msk = (kv0 + ct * 16 + r) > (q0 + g * 4 + reg);
                    s[ct][reg] = msk ? -1e30f : s[ct][reg] * scale;
                }
        } else {
#pragma unroll
            for (int ct = 0; ct < 4; ++ct)
#pragma unroll
                for (int reg = 0; reg < 4; ++reg) s[ct][reg] *= scale;
        }
        // row max over 64 kv: lane-local over ct, butterfly over 16-lane group
        float mx[4];
#pragma unroll
        for (int reg = 0; reg < 4; ++reg)
            mx[reg] = fmaxf(fmaxf(s[0][reg], s[1][reg]), fmaxf(s[2][reg], s[3][reg]));
#pragma unroll
        for (int off = 1; off < 16; off <<= 1)
#pragma unroll
            for (int reg = 0; reg < 4; ++reg)
                mx[reg] = fmaxf(mx[reg], __shfl_xor(mx[reg], off));

        float corr[4], mn[4], sm[4];
#pragma unroll
        for (int reg = 0; reg < 4; ++reg) {
            mn[reg] = fmaxf(m_[reg], mx[reg]);
            corr[reg] = __expf(m_[reg] - mn[reg]);
            m_[reg] = mn[reg];
            sm[reg] = 0.f;
        }
#pragma unroll
        for (int ct = 0; ct < 4; ++ct)
#pragma unroll
            for (int reg = 0; reg < 4; ++reg) {
                float p = __expf(s[ct][reg] - mn[reg]);
                s[ct][reg] = p;
                sm[reg] += p;
            }
#pragma unroll
        for (int off = 1; off < 16; off <<= 1)
#pragma unroll
            for (int reg = 0; reg < 4; ++reg)
                sm[reg] += __shfl_xor(sm[reg], off);
#pragma unroll
        for (int reg = 0; reg < 4; ++reg)
            l_[reg] = l_[reg] * corr[reg] + sm[reg];
#pragma unroll
        for (int ct = 0; ct < 4; ++ct)
#pragma unroll
            for (int reg = 0; reg < 4; ++reg)
                o[ct][reg] *= corr[reg];
        // P -> LDS (bf16, padded stride 72), then PV
#pragma unroll
        for (int ct = 0; ct < 4; ++ct)
#pragma unroll
            for (int reg = 0; reg < 4; ++reg)
                sP[(g * 4 + reg) * 72 + ct * 16 + r] = f2bf(s[ct][reg]);

        bf16x8 pa0 = *(bf16x8*)&sP[r * 72 + g * 8];
        bf16x8 pa1 = *(bf16x8*)&sP[r * 72 + 32 + g * 8];
#pragma unroll
        for (int cth = 0; cth < 4; ++cth) {
            const unsigned short* vp = &vt16[((b * 64 + cth * 16 + r) << 12) + kv0 + g * 8];
            bf16x8 bv0 = *(const bf16x8*)vp;
            bf16x8 bv1 = *(const bf16x8*)(vp + 32);
            o[cth] = __builtin_amdgcn_mfma_f32_16x16x32_bf16(pa0, bv0, o[cth], 0, 0, 0);
            o[cth] = __builtin_amdgcn_mfma_f32_16x16x32_bf16(pa1, bv1, o[cth], 0, 0, 0);
        }
    }
#pragma unroll
    for (int reg = 0; reg < 4; ++reg) {
        float inv = 1.0f / l_[reg];
        int orow = b * Tn + q0 + g * 4 + reg;
#pragma unroll
        for (int cth = 0; cth < 4; ++cth)
            out[orow * 64 + cth * 16 + r] = o[cth][reg] * inv;
    }
}

extern "C" void kernel_launch(void* const* d_in, const int* in_sizes, int n_in,
                              void* d_out, int out_size, void* d_ws, size_t ws_size,
                              hipStream_t stream) {
    const float* x  = (const float*)d_in[0];
    const float* Wq = (const float*)d_in[1];
    const float* Wk = (const float*)d_in[2];
    const float* Wv = (const float*)d_in[3];
    float* out = (float*)d_out;
    char* ws = (char*)d_ws;

    unsigned short* Wo  = (unsigned short*)ws;                       // 192*512*2   = 196608 B
    unsigned short* q16 = (unsigned short*)(ws + 196608);            // 16384*64*2  = 2 MiB
    unsigned short* k16 = (unsigned short*)(ws + 196608 + 2097152);
    unsigned short* v16 = (unsigned short*)(ws + 196608 + 2 * 2097152);
    // total ws use: ~6.2 MiB

    hipLaunchKernelGGL(wcvt, dim3(384), dim3(256), 0, stream, Wq, Wk, Wv, Wo);
    hipLaunchKernelGGL(proj, dim3(256), dim3(256), 0, stream, x, Wo, q16, k16, v16);
    hipLaunchKernelGGL(attn, dim3(1024), dim3(64), 0, stream, q16, k16, v16, out);
}

// Round 2
// 98.888 us; speedup vs baseline: 1.1561x; 1.1561x over previous
//
#include <hip/hip_runtime.h>
#include <hip/hip_bf16.h>

// B=4, T=4096, E=512, H=64. out fp32 [B,T,H].
#define Bn 4
#define Tn 4096
#define En 512
#define Hn 64

typedef __attribute__((ext_vector_type(8))) __bf16 bf16x8;
typedef __attribute__((ext_vector_type(4))) float f32x4;

__device__ __forceinline__ unsigned short f2bf(float f) {
    union { float f; unsigned u; } v; v.f = f;
    unsigned r = v.u + 0x7fffu + ((v.u >> 16) & 1u);
    return (unsigned short)(r >> 16);
}

// ---------------- kernel 1: W fp32 -> bf16 concat [192][512] ----------------
__global__ void wcvt(const float* __restrict__ Wq, const float* __restrict__ Wk,
                     const float* __restrict__ Wv, unsigned short* __restrict__ Wo) {
    int i = blockIdx.x * 256 + threadIdx.x;      // 0..98303
    int mat = i >> 15;                            // each W is 64*512 = 32768
    int off = i & 32767;
    const float* s = (mat == 0) ? Wq : ((mat == 1) ? Wk : Wv);
    Wo[i] = f2bf(s[off]);
}

// ---------------- kernel 2: fused QKV projection (bf16 MFMA GEMM) -----------
// y = x @ Wqkv^T : M=16384 rows, N=192 cols, K=512.
// cols 0-63 -> q[row][h], 64-127 -> k[row][h], 128-191 -> v^T[b][h][t].
__launch_bounds__(256, 2)
__global__ void proj(const float* __restrict__ x, const unsigned short* __restrict__ Wo,
                     unsigned short* __restrict__ q16, unsigned short* __restrict__ k16,
                     unsigned short* __restrict__ vt16) {
    __shared__ unsigned short sA[64 * 72];   // 64 rows x 64 k, stride 72 (pad kills bank conflict)
    __shared__ unsigned short sW[192 * 72];
    const int tid = threadIdx.x;
    const int w = tid >> 6, lane = tid & 63, r = lane & 15, g = lane >> 4;
    const int row0 = blockIdx.x * 64;

    f32x4 acc[12];
#pragma unroll
    for (int i = 0; i < 12; ++i) acc[i] = (f32x4){0.f, 0.f, 0.f, 0.f};

    for (int k0 = 0; k0 < En; k0 += 64) {
        // stage A: 64x64 fp32 -> bf16 (chunks of 8)
#pragma unroll
        for (int i = 0; i < 2; ++i) {
            int c = tid + i * 256; int arow = c >> 3, kc = (c & 7) * 8;
            const float4* xp = (const float4*)&x[(row0 + arow) * En + k0 + kc];
            float4 f0 = xp[0], f1 = xp[1];
            union { bf16x8 v; unsigned short u[8]; } t;
            t.u[0] = f2bf(f0.x); t.u[1] = f2bf(f0.y); t.u[2] = f2bf(f0.z); t.u[3] = f2bf(f0.w);
            t.u[4] = f2bf(f1.x); t.u[5] = f2bf(f1.y); t.u[6] = f2bf(f1.z); t.u[7] = f2bf(f1.w);
            *(bf16x8*)&sA[arow * 72 + kc] = t.v;
        }
        // stage W: 192x64 bf16
#pragma unroll
        for (int i = 0; i < 6; ++i) {
            int c = tid + i * 256; int wrow = c >> 3, kc = (c & 7) * 8;
            bf16x8 wv = *(const bf16x8*)&Wo[wrow * En + k0 + kc];
            *(bf16x8*)&sW[wrow * 72 + kc] = wv;
        }
        __syncthreads();
        bf16x8 a0 = *(bf16x8*)&sA[(w * 16 + r) * 72 + g * 8];
        bf16x8 a1 = *(bf16x8*)&sA[(w * 16 + r) * 72 + 32 + g * 8];
#pragma unroll
        for (int ct = 0; ct < 12; ++ct) {
            bf16x8 b0 = *(bf16x8*)&sW[(ct * 16 + r) * 72 + g * 8];
            bf16x8 b1 = *(bf16x8*)&sW[(ct * 16 + r) * 72 + 32 + g * 8];
            acc[ct] = __builtin_amdgcn_mfma_f32_16x16x32_bf16(a0, b0, acc[ct], 0, 0, 0);
            acc[ct] = __builtin_amdgcn_mfma_f32_16x16x32_bf16(a1, b1, acc[ct], 0, 0, 0);
        }
        __syncthreads();
    }
    // epilogue: C layout col = lane&15, row = (lane>>4)*4 + reg  (m89-verified)
#pragma unroll
    for (int ct = 0; ct < 12; ++ct) {
        int n = ct * 16 + r;
#pragma unroll
        for (int reg = 0; reg < 4; ++reg) {
            int gr = row0 + w * 16 + g * 4 + reg;
            unsigned short bv = f2bf(acc[ct][reg]);
            if (n < 64) {
                q16[gr * 64 + n] = bv;
            } else if (n < 128) {
                k16[gr * 64 + (n - 64)] = bv;
            } else {
                int h = n - 128; int bb = gr >> 12; int t = gr & 4095;
                vt16[((bb * 64 + h) << 12) + t] = bv;
            }
        }
    }
}

// ---------------- kernel 3: causal flash attention ---------------------------
// 1024 blocks x 4 waves (256 thr). Block = one 16-row q tile; the 4 waves
// split the KV range (wave w takes kv-tiles kb ≡ w mod 4, own online-softmax
// state), then merge partial (m,l,o) through LDS.
__launch_bounds__(256, 4)
__global__ void attn(const unsigned short* __restrict__ q16, const unsigned short* __restrict__ k16,
                     const unsigned short* __restrict__ vt16, float* __restrict__ out) {
    __shared__ unsigned short sP[4][16 * 72];
    __shared__ float oM[4][16][64];
    __shared__ float mM[4][16];
    __shared__ float lM[4][16];

    const int tid = threadIdx.x;
    const int w = tid >> 6, lane = tid & 63, r = lane & 15, g = lane >> 4;
    const int bid = blockIdx.x;
    const int b = (bid >> 1) & 3;                          // batch -> XCD pair (L2 locality)
    const int i16 = 255 - (((bid >> 3) << 1) | (bid & 1)); // longest tiles first
    const int q0 = i16 * 16;
    const int qrow = b * Tn + q0;

    bf16x8 aq0 = *(const bf16x8*)&q16[(qrow + r) * 64 + g * 8];
    bf16x8 aq1 = *(const bf16x8*)&q16[(qrow + r) * 64 + 32 + g * 8];

    f32x4 o[4];
#pragma unroll
    for (int i = 0; i < 4; ++i) o[i] = (f32x4){0.f, 0.f, 0.f, 0.f};
    float m_[4], l_[4];
#pragma unroll
    for (int i = 0; i < 4; ++i) { m_[i] = -1e30f; l_[i] = 0.f; }

    const int kbmax = i16 >> 2;
    const float scale = 0.125f;   // 1/sqrt(64)

    for (int kb = w; kb <= kbmax; kb += 4) {
        const int kv0 = kb * 64;
        f32x4 s[4];
#pragma unroll
        for (int ct = 0; ct < 4; ++ct) {
            const unsigned short* kp = &k16[(b * Tn + kv0 + ct * 16 + r) * 64 + g * 8];
            bf16x8 bk0 = *(const bf16x8*)kp;
            bf16x8 bk1 = *(const bf16x8*)(kp + 32);
            f32x4 t = (f32x4){0.f, 0.f, 0.f, 0.f};
            t = __builtin_amdgcn_mfma_f32_16x16x32_bf16(aq0, bk0, t, 0, 0, 0);
            t = __builtin_amdgcn_mfma_f32_16x16x32_bf16(aq1, bk1, t, 0, 0, 0);
            s[ct] = t;
        }
        if (kb == kbmax) {
#pragma unroll
            for (int ct = 0; ct < 4; ++ct)
#pragma unroll
                for (int reg = 0; reg < 4; ++reg) {
                    bool msk = (kv0 + ct * 16 + r) > (q0 + g * 4 + reg);
                    s[ct][reg] = msk ? -1e30f : s[ct][reg] * scale;
                }
        } else {
#pragma unroll
            for (int ct = 0; ct < 4; ++ct)
#pragma unroll
                for (int reg = 0; reg < 4; ++reg) s[ct][reg] *= scale;
        }
        // row max over 64 kv: lane-local over ct, butterfly over 16-lane group
        float mx[4];
#pragma unroll
        for (int reg = 0; reg < 4; ++reg)
            mx[reg] = fmaxf(fmaxf(s[0][reg], s[1][reg]), fmaxf(s[2][reg], s[3][reg]));
#pragma unroll
        for (int off = 1; off < 16; off <<= 1)
#pragma unroll
            for (int reg = 0; reg < 4; ++reg)
                mx[reg] = fmaxf(mx[reg], __shfl_xor(mx[reg], off));

        float corr[4], mn[4], sm[4];
#pragma unroll
        for (int reg = 0; reg < 4; ++reg) {
            mn[reg] = fmaxf(m_[reg], mx[reg]);
            corr[reg] = __expf(m_[reg] - mn[reg]);
            m_[reg] = mn[reg];
            sm[reg] = 0.f;
        }
#pragma unroll
        for (int ct = 0; ct < 4; ++ct)
#pragma unroll
            for (int reg = 0; reg < 4; ++reg) {
                float p = __expf(s[ct][reg] - mn[reg]);
                s[ct][reg] = p;
                sm[reg] += p;
            }
#pragma unroll
        for (int off = 1; off < 16; off <<= 1)
#pragma unroll
            for (int reg = 0; reg < 4; ++reg)
                sm[reg] += __shfl_xor(sm[reg], off);
#pragma unroll
        for (int reg = 0; reg < 4; ++reg)
            l_[reg] = l_[reg] * corr[reg] + sm[reg];
#pragma unroll
        for (int ct = 0; ct < 4; ++ct)
#pragma unroll
            for (int reg = 0; reg < 4; ++reg)
                o[ct][reg] *= corr[reg];
        // P -> LDS (bf16, padded stride 72, per-wave buffer), then PV
#pragma unroll
        for (int ct = 0; ct < 4; ++ct)
#pragma unroll
            for (int reg = 0; reg < 4; ++reg)
                sP[w][(g * 4 + reg) * 72 + ct * 16 + r] = f2bf(s[ct][reg]);

        bf16x8 pa0 = *(bf16x8*)&sP[w][r * 72 + g * 8];
        bf16x8 pa1 = *(bf16x8*)&sP[w][r * 72 + 32 + g * 8];
#pragma unroll
        for (int cth = 0; cth < 4; ++cth) {
            const unsigned short* vp = &vt16[((b * 64 + cth * 16 + r) << 12) + kv0 + g * 8];
            bf16x8 bv0 = *(const bf16x8*)vp;
            bf16x8 bv1 = *(const bf16x8*)(vp + 32);
            o[cth] = __builtin_amdgcn_mfma_f32_16x16x32_bf16(pa0, bv0, o[cth], 0, 0, 0);
            o[cth] = __builtin_amdgcn_mfma_f32_16x16x32_bf16(pa1, bv1, o[cth], 0, 0, 0);
        }
    }

    // ---- write per-wave partials to LDS ----
#pragma unroll
    for (int ct = 0; ct < 4; ++ct)
#pragma unroll
        for (int reg = 0; reg < 4; ++reg)
            oM[w][g * 4 + reg][ct * 16 + r] = o[ct][reg];
    if (r == 0) {
#pragma unroll
        for (int reg = 0; reg < 4; ++reg) {
            mM[w][g * 4 + reg] = m_[reg];
            lM[w][g * 4 + reg] = l_[reg];
        }
    }
    __syncthreads();

    // ---- merge: wave w handles rows w*4 + g; lane r covers cols r+16j ----
    {
        int rr = w * 4 + g;
        float m0 = mM[0][rr], m1 = mM[1][rr], m2 = mM[2][rr], m3 = mM[3][rr];
        float M = fmaxf(fmaxf(m0, m1), fmaxf(m2, m3));
        float w0 = __expf(m0 - M), w1 = __expf(m1 - M), w2 = __expf(m2 - M), w3 = __expf(m3 - M);
        float L = w0 * lM[0][rr] + w1 * lM[1][rr] + w2 * lM[2][rr] + w3 * lM[3][rr];
        float inv = 1.0f / L;
        int orow = b * Tn + q0 + rr;
#pragma unroll
        for (int j = 0; j < 4; ++j) {
            int col = r + 16 * j;
            float val = w0 * oM[0][rr][col] + w1 * oM[1][rr][col] +
                        w2 * oM[2][rr][col] + w3 * oM[3][rr][col];
            out[orow * 64 + col] = val * inv;
        }
    }
}

extern "C" void kernel_launch(void* const* d_in, const int* in_sizes, int n_in,
                              void* d_out, int out_size, void* d_ws, size_t ws_size,
                              hipStream_t stream) {
    const float* x  = (const float*)d_in[0];
    const float* Wq = (const float*)d_in[1];
    const float* Wk = (const float*)d_in[2];
    const float* Wv = (const float*)d_in[3];
    float* out = (float*)d_out;
    char* ws = (char*)d_ws;

    unsigned short* Wo  = (unsigned short*)ws;                       // 192*512*2   = 196608 B
    unsigned short* q16 = (unsigned short*)(ws + 196608);            // 16384*64*2  = 2 MiB
    unsigned short* k16 = (unsigned short*)(ws + 196608 + 2097152);
    unsigned short* v16 = (unsigned short*)(ws + 196608 + 2 * 2097152);
    // total ws use: ~6.2 MiB

    hipLaunchKernelGGL(wcvt, dim3(384), dim3(256), 0, stream, Wq, Wk, Wv, Wo);
    hipLaunchKernelGGL(proj, dim3(256), dim3(256), 0, stream, x, Wo, q16, k16, v16);
    hipLaunchKernelGGL(attn, dim3(1024), dim3(256), 0, stream, q16, k16, v16, out);
}